// Round 8
// baseline (165.822 us; speedup 1.0000x reference)
//
#include <hip/hip_runtime.h>
#include <math.h>

// StableSinkhornKnopp: B=16384 x K=1024 fp32.
// Q[k,b] = s * E[b,k] * r[k] * c[b],  E = exp((x-M')*20), M' = sampled max
// (max shift cancels in all normalizations). E cached once as bf16 (32 MiB).
// Validated structure (R3) with occupancy fixes:
//  - fat 1024-thread blocks in exp/col passes: 16 waves/CU (vs 8), same
//    512-block grid => SAME atomic count as R3 (512x1024/pass, NSPREAD=16)
//  - uint4 (16B/lane) E loads in col passes
//  - nontemporal out stores in final (don't evict E' from L2/L3)
//  - RACC zero via hipMemsetAsync (graph-safe), tiny glue kernels kept
// R4 lesson: no register-resident E (spills). R6 lesson: no __threadfence /
// in-kernel grid sync on gfx950 (XCD L2 writeback storm); kernel boundaries
// + tiny glue kernels are the cheap grid sync. R7 lesson: no redundant
// per-block derive_r (MBs of L2 traffic); 1us glue kernels win.

namespace {
constexpr int B_ROWS = 16384;
constexpr int K_COLS = 1024;
constexpr float INV_EPS = 20.0f;   // 1/0.05
constexpr float STAB = 1e-9f;
constexpr int NSPREAD = 16;

constexpr int OFF_M    = 0;        // sampled max (int-ordered float)
constexpr int OFF_S    = 1;        // s
constexpr int OFF_R    = 1024;     // r vector, 1024
constexpr int OFF_RACC = 2048;     // 3 x NSPREAD x 1024
constexpr int OFF_C    = 65536;    // c vector, 16384
constexpr size_t EB_BYTE_OFF = 1u << 20;  // bf16 E at ws+1MiB, 32 MiB
}

typedef float vfloat4 __attribute__((ext_vector_type(4)));

__device__ inline unsigned bf16rne(float f) {
  unsigned u = __float_as_uint(f);
  return (u + 0x7FFFu + ((u >> 16) & 1u)) >> 16;
}
__device__ inline float bf16tof(unsigned h) { return __uint_as_float(h << 16); }

// ---- K1: sampled max (4 MiB, 16 KiB stripes). 256 x 256 ----
__global__ void k_smax(const float* __restrict__ x, float* __restrict__ ws) {
  __shared__ float sm[4];
  int t = threadIdx.x;
  const float4* xb = (const float4*)x + (size_t)blockIdx.x * 16 * 1024;
  float4 v0 = xb[t], v1 = xb[t + 256], v2 = xb[t + 512], v3 = xb[t + 768];
  float m = fmaxf(fmaxf(fmaxf(v0.x, v0.y), fmaxf(v0.z, v0.w)),
                  fmaxf(fmaxf(v1.x, v1.y), fmaxf(v1.z, v1.w)));
  m = fmaxf(m, fmaxf(fmaxf(fmaxf(v2.x, v2.y), fmaxf(v2.z, v2.w)),
                     fmaxf(fmaxf(v3.x, v3.y), fmaxf(v3.z, v3.w))));
  #pragma unroll
  for (int off = 32; off > 0; off >>= 1) m = fmaxf(m, __shfl_xor(m, off, 64));
  if ((t & 63) == 0) sm[t >> 6] = m;
  __syncthreads();
  if (t == 0) {
    m = fmaxf(fmaxf(sm[0], sm[1]), fmaxf(sm[2], sm[3]));
    atomicMax((int*)(ws + OFF_M), __float_as_int(m));  // poison is negative int
  }
}

// ---- K2: E' = bf16(exp((x-M)*20)); R0 atomics. 512 blocks x 1024 threads ----
// Block: rows [32b,32b+32). Thread: tc=t&255 (cols 4tc..4tc+3), tr=t>>8
// (rows 8tr..8tr+8). 8 independent float4 loads; LDS fold over 4 row-groups.
__global__ __launch_bounds__(1024)
void k_exp_rowsum(const float* __restrict__ x, unsigned short* __restrict__ Eb,
                  float* __restrict__ ws) {
  __shared__ float lacc[4][1024];
  int t = threadIdx.x;
  int tc = t & 255, tr = t >> 8;
  float M = ws[OFF_M];
  const float* xb = x + ((size_t)blockIdx.x * 32 + 8 * tr) * K_COLS + 4 * tc;
  unsigned short* eb = Eb + ((size_t)blockIdx.x * 32 + 8 * tr) * K_COLS + 4 * tc;
  float a0 = 0.f, a1 = 0.f, a2 = 0.f, a3 = 0.f;
  #pragma unroll
  for (int half = 0; half < 2; ++half) {
    float4 v0 = *(const float4*)(xb + (size_t)(4 * half + 0) * K_COLS);
    float4 v1 = *(const float4*)(xb + (size_t)(4 * half + 1) * K_COLS);
    float4 v2 = *(const float4*)(xb + (size_t)(4 * half + 2) * K_COLS);
    float4 v3 = *(const float4*)(xb + (size_t)(4 * half + 3) * K_COLS);
    #pragma unroll
    for (int rr = 0; rr < 4; ++rr) {
      float4 v = (rr == 0) ? v0 : (rr == 1) ? v1 : (rr == 2) ? v2 : v3;
      unsigned h0 = bf16rne(__expf((v.x - M) * INV_EPS));
      unsigned h1 = bf16rne(__expf((v.y - M) * INV_EPS));
      unsigned h2 = bf16rne(__expf((v.z - M) * INV_EPS));
      unsigned h3 = bf16rne(__expf((v.w - M) * INV_EPS));
      ushort4 hs;
      hs.x = (unsigned short)h0; hs.y = (unsigned short)h1;
      hs.z = (unsigned short)h2; hs.w = (unsigned short)h3;
      *(ushort4*)(eb + (size_t)(4 * half + rr) * K_COLS) = hs;
      a0 += bf16tof(h0); a1 += bf16tof(h1); a2 += bf16tof(h2); a3 += bf16tof(h3);
    }
  }
  lacc[tr][4 * tc + 0] = a0;
  lacc[tr][4 * tc + 1] = a1;
  lacc[tr][4 * tc + 2] = a2;
  lacc[tr][4 * tc + 3] = a3;
  __syncthreads();
  float sum = lacc[0][t] + lacc[1][t] + lacc[2][t] + lacc[3][t];
  atomicAdd(&ws[OFF_RACC + (blockIdx.x & (NSPREAD - 1)) * 1024 + t], sum);
}

// ---- glue: fold R0 -> S -> s -> r1. 1 x 1024 ----
__global__ void k_init_r(float* __restrict__ ws) {
  __shared__ float sm[16];
  __shared__ float s_sh;
  int t = threadIdx.x;
  float R0t = 0.f;
  #pragma unroll
  for (int i = 0; i < NSPREAD; ++i) R0t += ws[OFF_RACC + i * 1024 + t];
  float p = R0t;
  #pragma unroll
  for (int off = 32; off > 0; off >>= 1) p += __shfl_xor(p, off, 64);
  if ((t & 63) == 0) sm[t >> 6] = p;
  __syncthreads();
  if (t == 0) {
    float S = 0.f;
    #pragma unroll
    for (int i = 0; i < 16; ++i) S += sm[i];
    float s = 1.0f / (S + STAB);
    ws[OFF_S] = s;
    s_sh = s;
  }
  __syncthreads();
  ws[OFF_R + t] = 1.0f / ((s_sh * R0t + STAB) * K_COLS);
}

// ---- K3: col-normalize + next row-sum. 512 blocks x 1024 threads ----
// Block: rows [32b,32b+32). Wave w (0..15): rows 32b+2w, +1. Lane: cols
// [8l,8l+8) and [512+8l,512+8l+8) via uint4. LDS fold over 16 waves.
__global__ __launch_bounds__(1024)
void k_col(const unsigned short* __restrict__ Eb, float* __restrict__ ws,
           float* __restrict__ Racc, int first) {
  __shared__ float lacc[16][1024];
  __shared__ float r_sh[1024];
  int t = threadIdx.x;
  int lane = t & 63;
  int wv = t >> 6;
  float s = ws[OFF_S];
  if (t < 256) ((float4*)r_sh)[t] = ((const float4*)(ws + OFF_R))[t];
  __syncthreads();

  float rv[16];
  {
    float4 ra = *(const float4*)&r_sh[8 * lane];
    float4 rb = *(const float4*)&r_sh[8 * lane + 4];
    float4 rc = *(const float4*)&r_sh[512 + 8 * lane];
    float4 rd = *(const float4*)&r_sh[512 + 8 * lane + 4];
    rv[0] = ra.x; rv[1] = ra.y; rv[2] = ra.z; rv[3] = ra.w;
    rv[4] = rb.x; rv[5] = rb.y; rv[6] = rb.z; rv[7] = rb.w;
    rv[8] = rc.x; rv[9] = rc.y; rv[10] = rc.z; rv[11] = rc.w;
    rv[12] = rd.x; rv[13] = rd.y; rv[14] = rd.z; rv[15] = rd.w;
  }

  int row0 = blockIdx.x * 32 + 2 * wv;
  const unsigned short* e0p = Eb + (size_t)row0 * K_COLS + 8 * lane;
  const unsigned short* e1p = e0p + K_COLS;
  uint4 A0 = *(const uint4*)(e0p);
  uint4 A1 = *(const uint4*)(e0p + 512);
  uint4 B0 = *(const uint4*)(e1p);
  uint4 B1 = *(const uint4*)(e1p + 512);

  float e0[16], e1[16];
  e0[0]=bf16tof(A0.x&0xFFFFu); e0[1]=bf16tof(A0.x>>16);
  e0[2]=bf16tof(A0.y&0xFFFFu); e0[3]=bf16tof(A0.y>>16);
  e0[4]=bf16tof(A0.z&0xFFFFu); e0[5]=bf16tof(A0.z>>16);
  e0[6]=bf16tof(A0.w&0xFFFFu); e0[7]=bf16tof(A0.w>>16);
  e0[8]=bf16tof(A1.x&0xFFFFu); e0[9]=bf16tof(A1.x>>16);
  e0[10]=bf16tof(A1.y&0xFFFFu); e0[11]=bf16tof(A1.y>>16);
  e0[12]=bf16tof(A1.z&0xFFFFu); e0[13]=bf16tof(A1.z>>16);
  e0[14]=bf16tof(A1.w&0xFFFFu); e0[15]=bf16tof(A1.w>>16);
  e1[0]=bf16tof(B0.x&0xFFFFu); e1[1]=bf16tof(B0.x>>16);
  e1[2]=bf16tof(B0.y&0xFFFFu); e1[3]=bf16tof(B0.y>>16);
  e1[4]=bf16tof(B0.z&0xFFFFu); e1[5]=bf16tof(B0.z>>16);
  e1[6]=bf16tof(B0.w&0xFFFFu); e1[7]=bf16tof(B0.w>>16);
  e1[8]=bf16tof(B1.x&0xFFFFu); e1[9]=bf16tof(B1.x>>16);
  e1[10]=bf16tof(B1.y&0xFFFFu); e1[11]=bf16tof(B1.y>>16);
  e1[12]=bf16tof(B1.z&0xFFFFu); e1[13]=bf16tof(B1.z>>16);
  e1[14]=bf16tof(B1.w&0xFFFFu); e1[15]=bf16tof(B1.w>>16);

  float p0 = 0.f, p1 = 0.f;
  #pragma unroll
  for (int i = 0; i < 16; ++i) { p0 += e0[i] * rv[i]; p1 += e1[i] * rv[i]; }
  #pragma unroll
  for (int off = 32; off > 0; off >>= 1) {
    p0 += __shfl_xor(p0, off, 64);
    p1 += __shfl_xor(p1, off, 64);
  }
  float* c = ws + OFF_C;
  float c0in = first ? 1.0f : c[row0];
  float c1in = first ? 1.0f : c[row0 + 1];
  float c0n = c0in / ((s * c0in * p0 + STAB) * B_ROWS);
  float c1n = c1in / ((s * c1in * p1 + STAB) * B_ROWS);
  if (lane == 0) { c[row0] = c0n; c[row0 + 1] = c1n; }

  float acc[16];
  #pragma unroll
  for (int i = 0; i < 16; ++i) acc[i] = e0[i] * c0n + e1[i] * c1n;
  *(float4*)&lacc[wv][8 * lane]           = *(float4*)&acc[0];
  *(float4*)&lacc[wv][8 * lane + 4]       = *(float4*)&acc[4];
  *(float4*)&lacc[wv][512 + 8 * lane]     = *(float4*)&acc[8];
  *(float4*)&lacc[wv][512 + 8 * lane + 4] = *(float4*)&acc[12];
  __syncthreads();
  float sum = 0.f;
  #pragma unroll
  for (int w = 0; w < 16; ++w) sum += lacc[w][t];
  atomicAdd(&Racc[(blockIdx.x & (NSPREAD - 1)) * 1024 + t], sum);
}

// ---- glue: r_new[k] = r[k]/((s*r[k]*R[k]+eps)*K). 1 x 1024 ----
__global__ void k_upd_r(float* __restrict__ ws, const float* __restrict__ Racc) {
  int t = threadIdx.x;
  float A = 0.f;
  #pragma unroll
  for (int i = 0; i < NSPREAD; ++i) A += Racc[i * 1024 + t];
  float s = ws[OFF_S];
  float rv = ws[OFF_R + t];
  ws[OFF_R + t] = rv / ((s * rv * A + STAB) * K_COLS);
}

// ---- K4: final col-normalize + out (nontemporal). 2048 x 256; wave=2 rows ----
__global__ void k_final(const unsigned short* __restrict__ Eb,
                        float* __restrict__ ws, float* __restrict__ out) {
  __shared__ float r_sh[1024];
  int t = threadIdx.x;
  int lane = t & 63;
  int wv = t >> 6;
  float s = ws[OFF_S];
  ((float4*)r_sh)[t] = ((const float4*)(ws + OFF_R))[t];
  __syncthreads();

  float rv[16];
  {
    float4 ra = *(const float4*)&r_sh[8 * lane];
    float4 rb = *(const float4*)&r_sh[8 * lane + 4];
    float4 rc = *(const float4*)&r_sh[512 + 8 * lane];
    float4 rd = *(const float4*)&r_sh[512 + 8 * lane + 4];
    rv[0] = ra.x; rv[1] = ra.y; rv[2] = ra.z; rv[3] = ra.w;
    rv[4] = rb.x; rv[5] = rb.y; rv[6] = rb.z; rv[7] = rb.w;
    rv[8] = rc.x; rv[9] = rc.y; rv[10] = rc.z; rv[11] = rc.w;
    rv[12] = rd.x; rv[13] = rd.y; rv[14] = rd.z; rv[15] = rd.w;
  }

  int row0 = blockIdx.x * 8 + 2 * wv;
  const unsigned short* e0p = Eb + (size_t)row0 * K_COLS + 8 * lane;
  const unsigned short* e1p = e0p + K_COLS;
  uint4 A0 = *(const uint4*)(e0p);
  uint4 A1 = *(const uint4*)(e0p + 512);
  uint4 B0 = *(const uint4*)(e1p);
  uint4 B1 = *(const uint4*)(e1p + 512);

  float e0[16], e1[16];
  e0[0]=bf16tof(A0.x&0xFFFFu); e0[1]=bf16tof(A0.x>>16);
  e0[2]=bf16tof(A0.y&0xFFFFu); e0[3]=bf16tof(A0.y>>16);
  e0[4]=bf16tof(A0.z&0xFFFFu); e0[5]=bf16tof(A0.z>>16);
  e0[6]=bf16tof(A0.w&0xFFFFu); e0[7]=bf16tof(A0.w>>16);
  e0[8]=bf16tof(A1.x&0xFFFFu); e0[9]=bf16tof(A1.x>>16);
  e0[10]=bf16tof(A1.y&0xFFFFu); e0[11]=bf16tof(A1.y>>16);
  e0[12]=bf16tof(A1.z&0xFFFFu); e0[13]=bf16tof(A1.z>>16);
  e0[14]=bf16tof(A1.w&0xFFFFu); e0[15]=bf16tof(A1.w>>16);
  e1[0]=bf16tof(B0.x&0xFFFFu); e1[1]=bf16tof(B0.x>>16);
  e1[2]=bf16tof(B0.y&0xFFFFu); e1[3]=bf16tof(B0.y>>16);
  e1[4]=bf16tof(B0.z&0xFFFFu); e1[5]=bf16tof(B0.z>>16);
  e1[6]=bf16tof(B0.w&0xFFFFu); e1[7]=bf16tof(B0.w>>16);
  e1[8]=bf16tof(B1.x&0xFFFFu); e1[9]=bf16tof(B1.x>>16);
  e1[10]=bf16tof(B1.y&0xFFFFu); e1[11]=bf16tof(B1.y>>16);
  e1[12]=bf16tof(B1.z&0xFFFFu); e1[13]=bf16tof(B1.z>>16);
  e1[14]=bf16tof(B1.w&0xFFFFu); e1[15]=bf16tof(B1.w>>16);

  float p0 = 0.f, p1 = 0.f;
  #pragma unroll
  for (int i = 0; i < 16; ++i) { p0 += e0[i] * rv[i]; p1 += e1[i] * rv[i]; }
  #pragma unroll
  for (int off = 32; off > 0; off >>= 1) {
    p0 += __shfl_xor(p0, off, 64);
    p1 += __shfl_xor(p1, off, 64);
  }
  const float* c = ws + OFF_C;
  float c0in = c[row0];
  float c1in = c[row0 + 1];
  float c0n = c0in / ((s * c0in * p0 + STAB) * B_ROWS);
  float c1n = c1in / ((s * c1in * p1 + STAB) * B_ROWS);
  float f0 = s * c0n * B_ROWS;
  float f1 = s * c1n * B_ROWS;

  float* o0 = out + (size_t)row0 * K_COLS + 8 * lane;
  float* o1 = o0 + K_COLS;
  vfloat4 u;
  u[0] = e0[0]*rv[0]*f0; u[1] = e0[1]*rv[1]*f0; u[2] = e0[2]*rv[2]*f0; u[3] = e0[3]*rv[3]*f0;
  __builtin_nontemporal_store(u, (vfloat4*)(o0));
  u[0] = e0[4]*rv[4]*f0; u[1] = e0[5]*rv[5]*f0; u[2] = e0[6]*rv[6]*f0; u[3] = e0[7]*rv[7]*f0;
  __builtin_nontemporal_store(u, (vfloat4*)(o0 + 4));
  u[0] = e0[8]*rv[8]*f0; u[1] = e0[9]*rv[9]*f0; u[2] = e0[10]*rv[10]*f0; u[3] = e0[11]*rv[11]*f0;
  __builtin_nontemporal_store(u, (vfloat4*)(o0 + 512));
  u[0] = e0[12]*rv[12]*f0; u[1] = e0[13]*rv[13]*f0; u[2] = e0[14]*rv[14]*f0; u[3] = e0[15]*rv[15]*f0;
  __builtin_nontemporal_store(u, (vfloat4*)(o0 + 516));
  u[0] = e1[0]*rv[0]*f1; u[1] = e1[1]*rv[1]*f1; u[2] = e1[2]*rv[2]*f1; u[3] = e1[3]*rv[3]*f1;
  __builtin_nontemporal_store(u, (vfloat4*)(o1));
  u[0] = e1[4]*rv[4]*f1; u[1] = e1[5]*rv[5]*f1; u[2] = e1[6]*rv[6]*f1; u[3] = e1[7]*rv[7]*f1;
  __builtin_nontemporal_store(u, (vfloat4*)(o1 + 4));
  u[0] = e1[8]*rv[8]*f1; u[1] = e1[9]*rv[9]*f1; u[2] = e1[10]*rv[10]*f1; u[3] = e1[11]*rv[11]*f1;
  __builtin_nontemporal_store(u, (vfloat4*)(o1 + 512));
  u[0] = e1[12]*rv[12]*f1; u[1] = e1[13]*rv[13]*f1; u[2] = e1[14]*rv[14]*f1; u[3] = e1[15]*rv[15]*f1;
  __builtin_nontemporal_store(u, (vfloat4*)(o1 + 516));
}

extern "C" void kernel_launch(void* const* d_in, const int* in_sizes, int n_in,
                              void* d_out, int out_size, void* d_ws, size_t ws_size,
                              hipStream_t stream) {
  const float* x = (const float*)d_in[0];
  float* out = (float*)d_out;
  float* ws = (float*)d_ws;
  unsigned short* Eb = (unsigned short*)((char*)d_ws + EB_BYTE_OFF);
  (void)in_sizes; (void)n_in; (void)out_size; (void)ws_size;

  float* R1 = ws + OFF_RACC + NSPREAD * 1024;
  float* R2 = ws + OFF_RACC + 2 * NSPREAD * 1024;

  hipMemsetAsync(ws + OFF_RACC, 0, (size_t)3 * NSPREAD * 1024 * sizeof(float),
                 stream);
  k_smax<<<256, 256, 0, stream>>>(x, ws);
  k_exp_rowsum<<<512, 1024, 0, stream>>>(x, Eb, ws);   // E', R0
  k_init_r<<<1, 1024, 0, stream>>>(ws);                // s, r1
  k_col<<<512, 1024, 0, stream>>>(Eb, ws, R1, 1);      // c1, R1
  k_upd_r<<<1, 1024, 0, stream>>>(ws, R1);             // r2
  k_col<<<512, 1024, 0, stream>>>(Eb, ws, R2, 0);      // c2, R2
  k_upd_r<<<1, 1024, 0, stream>>>(ws, R2);             // r3
  k_final<<<2048, 256, 0, stream>>>(Eb, ws, out);      // c3 + out
}